// Round 4
// baseline (586.109 us; speedup 1.0000x reference)
//
#include <hip/hip_runtime.h>
#include <hip/hip_fp16.h>

#define NB 512   // batch
#define NT 512   // time steps
#define NL 126   // labels
#define NS 128   // states (start=126, end=127)
#define SIGMA 0.0625f   // lagged-normalizer target scale (1/16)

typedef _Float16 h2 __attribute__((ext_vector_type(2)));

static __device__ __forceinline__ int pk_from(float a, float b) {
  return __builtin_bit_cast(int, __builtin_amdgcn_cvt_pkrtz(a, b));
}
// guaranteed-packed fp16 ops on int-carried pairs
static __device__ __forceinline__ int pkmul(int a, int b) {
  int d; asm("v_pk_mul_f16 %0, %1, %2" : "=v"(d) : "v"(a), "v"(b)); return d;
}
static __device__ __forceinline__ int pkmax(int a, int b) {
  int d; asm("v_pk_max_f16 %0, %1, %2" : "=v"(d) : "v"(a), "v"(b)); return d;
}
static __device__ __forceinline__ int pkadd(int a, int b) {
  int d; asm("v_pk_add_f16 %0, %1, %2" : "=v"(d) : "v"(a), "v"(b)); return d;
}

// wave64 add-reduce to lane 63, ONE instruction per stage (v_add_f32_dpp).
// Same numeric tree as the validated R0-R3 macro.
#define WAVE_ADD(x) do { \
  asm("v_add_f32_dpp %0, %0, %0 row_shr:1  row_mask:0xf bank_mask:0xf bound_ctrl:0" : "+v"(x)); \
  asm("v_add_f32_dpp %0, %0, %0 row_shr:2  row_mask:0xf bank_mask:0xf bound_ctrl:0" : "+v"(x)); \
  asm("v_add_f32_dpp %0, %0, %0 row_shr:4  row_mask:0xf bank_mask:0xf bound_ctrl:0" : "+v"(x)); \
  asm("v_add_f32_dpp %0, %0, %0 row_shr:8  row_mask:0xf bank_mask:0xf bound_ctrl:0" : "+v"(x)); \
  asm("v_add_f32_dpp %0, %0, %0 row_bcast:15 row_mask:0xa bank_mask:0xf bound_ctrl:0" : "+v"(x)); \
  asm("v_add_f32_dpp %0, %0, %0 row_bcast:31 row_mask:0xc bank_mask:0xf bound_ctrl:0" : "+v"(x)); \
} while (0)

// Light barrier: drain LDS ops (cross-wave u/partial visibility) but leave the
// global emission prefetch IN FLIGHT across the barrier — __syncthreads would
// s_waitcnt vmcnt(0) and stall every step on the HBM prefetch (T4 lesson).
// No cross-wave global traffic exists inside the loop, so lgkmcnt-only is safe.
#define LIGHT_BARRIER() do { \
  asm volatile("s_waitcnt lgkmcnt(0)" ::: "memory"); \
  __builtin_amdgcn_s_barrier(); \
  asm volatile("" ::: "memory"); \
} while (0)

// TWO waves per batch element; lane (wave w, lane l) owns column 64w+l, all
// 128 rows (tab = 64 packed ints/lane, no spill at VGPR~136). u-exchange via
// 256B LDS ping-pong + one light barrier per step. Z (normalizer) reduction is
// 1-step lagged (validated R3 dynamics, bit-identical u path). The contrib/Cc
// reduction is deferred one step: its 6-stage DPP chain runs at the TOP of the
// next iteration, interleaved with that step's pk tree — off the pre-barrier
// critical path. Cc accumulation order is unchanged (virtual steps add
// log(1)=0 exactly), so output is bit-identical to R3.
__global__ __launch_bounds__(128) __attribute__((amdgpu_waves_per_eu(1, 1)))
void crf_kernel(
    const float* __restrict__ emissions,   // [NB, NT, NL]
    const int*   __restrict__ labels,      // [NB, NT]
    const float* __restrict__ trans,       // [NS, NS]
    float*       __restrict__ out)
{
  const int b   = blockIdx.x;
  const int tid = threadIdx.x;            // 0..127
  const int wv  = tid >> 6;               // wave 0..1
  const int ln  = tid & 63;
  const int col = tid;                    // column 0..127 owned by this lane
  const bool has = (col < NL);

  __shared__ __align__(16) _Float16 u_sh[2][NS];  // ping-pong u buffers, 256B each
  __shared__ float sPartC[2][2];                  // deferred contrib partials [slot][wave]
  __shared__ float zPart[2][2];                   // Z partials [slot][wave] (1-step lag)
  __shared__ float fin[2];

  const float* em  = emissions + (size_t)b * NT * NL;
  const int*   lab = labels + (size_t)b * NT;

  // ---- per-column max tau (exact fp32) ----
  float tau = -3.0e38f;
  for (int rr = 0; rr < NS; rr++) tau = fmaxf(tau, trans[rr * NS + col]);

  // ---- tab[k] = rows (2k, 2k+1) of exp(T[.][col]-tau), packed fp16 ----
  int tab[64];
  #pragma unroll
  for (int k = 0; k < 64; k++) {
    float t0 = __expf(trans[(2 * k) * NS + col] - tau);
    float t1 = __expf(trans[(2 * k + 1) * NS + col] - tau);
    tab[k] = pk_from(t0, t1);
  }

  // ---- gold path partial (4 timesteps per thread) ----
  float realp = 0.f;
  #pragma unroll
  for (int q = 0; q < NT / 128; q++) {
    int t  = tid + q * 128;
    int la = lab[t];
    int na = (t + 1 < NT) ? lab[t + 1] : (NL + 1);
    realp += em[t * NL + la] + trans[la * NS + na];
  }
  if (tid == 0) realp += trans[NL * NS + lab[0]];

  // ---- init: v = delta at start state (col 126), buffer 0 ----
  u_sh[0][col] = (_Float16)((col == NL) ? 1.f : 0.f);
  // virtual contrib S_{-1} = 1 in slot 1 (read at t=1... see slot discipline)
  if (tid < 2) sPartC[1][tid] = 0.5f;
  float cS = 1.f / 128.f;   // t=0's deferred reduce writes S=1 into slot 0

  // ---- rolling 2-deep emission prefetch (4B per lane, coalesced) ----
  float emc = has ? em[col] : 0.f;
  float emn = has ? em[NL + col] : 0.f;
  const float* emp = em + 2 * NL + col;   // pointer-bump t+2 prefetch address

  float Cc = 0.f, Q = 0.f;
  __syncthreads();

  #pragma unroll 2
  for (int t = 0; t <= NT; t++) {
    const int sl = t & 1;

    // ---- deferred contrib reduce for step t-1 (interleaves with the tree) ----
    WAVE_ADD(cS);
    if (ln == 63) sPartC[sl][wv] = cS;
    // lagged Cc log: S_{t-2} (slot sl^1; t=0,1 read preinit 1 -> log adds 0)
    Cc += __logf(sPartC[sl ^ 1][0] + sPartC[sl ^ 1][1]);

    // ---- lagged Z scalar from step t-1 (slot t&1), unchanged R3 dynamics ----
    float r;
    if (t > 0) {
      float Z = zPart[sl][0] + zPart[sl][1];
      Q += __logf(Z);
      r = SIGMA * __builtin_amdgcn_rcpf(Z);
    } else {
      r = SIGMA;                       // Z(init) = 1
    }

    // ---- g = exp(obs + tau) from prefetched emission ----
    float obs;
    if (t < NT) obs = has ? emc : -1000.f;
    else        obs = (col == NL + 1) ? 0.f : -1000.f;
    float g = __expf(obs + tau);

    // issue t+2 emission prefetch early (stays in flight across the barrier)
    float ef = 0.f;
    if (t + 2 < NT && has) ef = *emp;
    emp += NL;
    emc = emn; emn = ef;

    // ---- broadcast-read the whole u vector (16x same-address b128) ----
    const int4* up = (const int4*)u_sh[sl];
    int4 uu[16];
    #pragma unroll
    for (int j = 0; j < 16; j++) uu[j] = up[j];

    // ---- critical path: 128 rows of this lane's column, 8 acc chains ----
    int ha = 0, hb = 0, hcc = 0, hd = 0;
    int sa = 0, sb = 0, scc = 0, sd = 0;
    #pragma unroll
    for (int j = 0; j < 16; j++) {
      int m;
      m = pkmul(uu[j].x, tab[4*j+0]); ha  = pkmax(ha,  m); sa  = pkadd(sa,  m);
      m = pkmul(uu[j].y, tab[4*j+1]); hb  = pkmax(hb,  m); sb  = pkadd(sb,  m);
      m = pkmul(uu[j].z, tab[4*j+2]); hcc = pkmax(hcc, m); scc = pkadd(scc, m);
      m = pkmul(uu[j].w, tab[4*j+3]); hd  = pkmax(hd,  m); sd  = pkadd(sd,  m);
    }
    int hv = pkmax(pkmax(ha, hb), pkmax(hcc, hd));
    int sv = pkadd(pkadd(sa, sb), pkadd(scc, sd));
    h2 hh = __builtin_bit_cast(h2, hv);
    h2 ss = __builtin_bit_cast(h2, sv);
    float h = fmaxf(fmaxf((float)hh.x, (float)hh.y), 1e-30f);
    float s = (float)ss.x + (float)ss.y;

    float w = h * g;
    float v = w * r;
    u_sh[sl ^ 1][col] = (_Float16)v;   // single b16 write per lane

    // ---- Z reduction (must finish this step: feeds r at t+1) ----
    float zz = v;
    WAVE_ADD(zz);
    if (ln == 63) zPart[sl ^ 1][wv] = zz;

    // contrib for step t: reduced at the TOP of step t+1 (deferred)
    cS = s * __builtin_amdgcn_rcpf(h);

    LIGHT_BARRIER();                   // lgkmcnt drain only; vmcnt stays live
  }

  // ---- tail: step NT's contrib (in regs) + S_{NT-1} (slot 0) + Z_NT ----
  WAVE_ADD(cS);
  if (ln == 63) sPartC[1][wv] = cS;    // slot 1 free after its last read at t=NT
  __syncthreads();
  Cc += __logf(sPartC[0][0] + sPartC[0][1]);   // S_{NT-1}
  Cc += __logf(sPartC[1][0] + sPartC[1][1]);   // S_NT
  {
    float Z = zPart[1][0] + zPart[1][1];       // Z_NT
    Q += __logf(Z);
  }

  // total = Cc + Q + (NT+1)*log(1/SIGMA); one atomic per block
  WAVE_ADD(realp);
  if (ln == 63) fin[wv] = realp;
  __syncthreads();
  if (tid == 0) {
    const float CONST = 513.f * 2.772588722f;   // (NT+1) * log 16
    atomicAdd(out, (Cc + Q + CONST) - (fin[0] + fin[1]));
  }
}

extern "C" void kernel_launch(void* const* d_in, const int* in_sizes, int n_in,
                              void* d_out, int out_size, void* d_ws, size_t ws_size,
                              hipStream_t stream) {
  const float* em  = (const float*)d_in[0];
  const int*   lab = (const int*)d_in[1];
  const float* tr  = (const float*)d_in[2];
  (void)hipMemsetAsync(d_out, 0, sizeof(float), stream);
  crf_kernel<<<NB, 128, 0, stream>>>(em, lab, tr, (float*)d_out);
}